// Round 5
// baseline (8121.723 us; speedup 1.0000x reference)
//
#include <hip/hip_runtime.h>
#include <hip/hip_fp16.h>

// Problem constants
#define L_SEQ 576
#define BATCH 16
#define HIDDEN 800
#define NT 200      // N tiles per direction (3200/16)
#define KQ_HH 25    // K chunks for W_hh (800/32)
#define KQ_L1 50    // 1600/32
#define KQ_L0 2     // padded 64/32

typedef _Float16 h8 __attribute__((ext_vector_type(8)));
typedef _Float16 h4 __attribute__((ext_vector_type(4)));
typedef float f4 __attribute__((ext_vector_type(4)));
typedef int v4i __attribute__((ext_vector_type(4)));
typedef int v2i __attribute__((ext_vector_type(2)));

__device__ __forceinline__ float sigmoidf_(float x){
  x = fminf(30.f, fmaxf(-30.f, x));
  return 1.f/(1.f+__expf(-x));
}
__device__ __forceinline__ float tanhf_(float x){
  x = fminf(15.f, fmaxf(-15.f, x));
  float e = __expf(2.f*x);
  return (e-1.f)/(e+1.f);
}

// ---------------- init: zero the per-(layer,dir) flag regions ---------------
// 1024 words: layer0 fwd [0..199], layer0 bwd [256..455],
//             layer1 fwd [512..711], layer1 bwd [768..967]
__global__ void init_kernel(int* flags){
  int i = blockIdx.x*256 + threadIdx.x;
  if(i < 1024) flags[i] = 0;
}

// ---------------- build x (L*B, 64) f16: [onehot(20) | pssm(21) | pad0] -----
__global__ void build_x(const int* __restrict__ seq, const float* __restrict__ pssm,
                        _Float16* __restrict__ x){
  int i = blockIdx.x*256 + threadIdx.x;
  if(i >= L_SEQ*BATCH*64) return;
  int m = i >> 6, k = i & 63;
  float v = 0.f;
  if(k < 20)      v = (seq[m]==k) ? 1.f : 0.f;
  else if(k < 41) v = pssm[m*21 + (k-20)];
  x[i] = (_Float16)v;
}

// ---------------- weight prep: fp32 -> f16 MFMA B-fragment layout ------------
// B-frag: lane l holds B[k=q*32+(l>>4)*8+j][n = tile*16 + (l&15)], j=0..7
// n-permutation: col c=l&15 -> unit u = T*4 + (c>>2), gate g = c&3, W row = g*800+u
__global__ void prep_w(
  const float* __restrict__ whh0f, const float* __restrict__ whh0b,
  const float* __restrict__ whh1f, const float* __restrict__ whh1b,
  const float* __restrict__ wih1f, const float* __restrict__ wih1b,
  const float* __restrict__ wih0f, const float* __restrict__ wih0b,
  h8* __restrict__ wp_hh, h8* __restrict__ wp1, h8* __restrict__ wp0)
{
  long idx = (long)blockIdx.x*256 + threadIdx.x;
  const long J1 = 4L*320000, J2 = 2L*640000, J3 = 2L*25600;
  if(idx < J1){
    int d = (int)(idx/320000); int r = (int)(idx%320000);
    int T = r/1600, q = (r%1600)/64, l = r&63;
    const float* W = (d==0)?whh0f:(d==1)?whh0b:(d==2)?whh1f:whh1b;
    int c = l&15; int n = (c&3)*800 + T*4 + (c>>2);
    const float* src = W + (size_t)n*800 + q*32 + ((l>>4)<<3);
    h8 v;
    #pragma unroll
    for(int j=0;j<8;++j) v[j] = (_Float16)src[j];
    wp_hh[idx] = v;
  } else if(idx < J1+J2){
    long i2 = idx - J1;
    int d = (int)(i2/640000); int r = (int)(i2%640000);
    int T = r/3200, q = (r%3200)/64, l = r&63;
    const float* W = d ? wih1b : wih1f;
    int c = l&15; int n = (c&3)*800 + T*4 + (c>>2);
    const float* src = W + (size_t)n*1600 + q*32 + ((l>>4)<<3);
    h8 v;
    #pragma unroll
    for(int j=0;j<8;++j) v[j] = (_Float16)src[j];
    wp1[i2] = v;
  } else if(idx < J1+J2+J3){
    long i3 = idx - J1 - J2;
    int d = (int)(i3/25600); int r = (int)(i3%25600);
    int T = r/128, q = (r%128)/64, l = r&63;
    const float* W = d ? wih0b : wih0f;
    int c = l&15; int n = (c&3)*800 + T*4 + (c>>2);
    int k0 = q*32 + ((l>>4)<<3);
    h8 v;
    #pragma unroll
    for(int j=0;j<8;++j){ int k = k0+j; v[j] = (_Float16)((k<41)? W[(size_t)n*41+k] : 0.f); }
    wp0[i3] = v;
  }
}

// ------------- layer-0 input projection (x row-major, lda=64) ---------------
__global__ __launch_bounds__(256) void gemm_l0(
  const _Float16* __restrict__ A,
  const h8* __restrict__ WpF, const h8* __restrict__ WpB,
  const float* __restrict__ bihF, const float* __restrict__ bhhF,
  const float* __restrict__ bihB, const float* __restrict__ bhhB,
  _Float16* __restrict__ GpF, _Float16* __restrict__ GpB)
{
  const int wv = threadIdx.x >> 6;
  const int l  = threadIdx.x & 63;
  const int mg = blockIdx.x % 144;
  const int tg = blockIdx.x / 144;       // 0..99
  const int mt = mg*4 + wv;              // 0..575
  const int dir = tg / 50;
  const int Tb  = (tg % 50) * 4;
  const h8* Wp = dir ? WpB : WpF;
  const float* bih = dir ? bihB : bihF;
  const float* bhh = dir ? bhhB : bhhF;
  _Float16* Gp = dir ? GpB : GpF;

  const _Float16* ab = A + (size_t)(mt*16 + (l&15))*64 + ((l>>4)<<3);
  f4 acc[4] = {{0.f,0.f,0.f,0.f},{0.f,0.f,0.f,0.f},{0.f,0.f,0.f,0.f},{0.f,0.f,0.f,0.f}};
  for(int q=0;q<KQ_L0;++q){
    h8 av = *(const h8*)(ab + q*32);
    #pragma unroll
    for(int j=0;j<4;++j){
      h8 bv = Wp[((size_t)(Tb+j)*KQ_L0 + q)*64 + l];
      acc[j] = __builtin_amdgcn_mfma_f32_16x16x32_f16(av, bv, acc[j], 0, 0, 0);
    }
  }
  const int c = l & 15;
  #pragma unroll
  for(int j=0;j<4;++j){
    int T = Tb + j;
    int n = (c&3)*800 + T*4 + (c>>2);
    float bias = bih[n] + bhh[n];
    h4 o;
    o[0]=(_Float16)(acc[j][0]+bias); o[1]=(_Float16)(acc[j][1]+bias);
    o[2]=(_Float16)(acc[j][2]+bias); o[3]=(_Float16)(acc[j][3]+bias);
    *(h4*)(Gp + (((size_t)mt*NT + T)*64 + l)*4) = o;
  }
}

// ------------- layer-1 input projection (h0 in fragment layout) --------------
// 2 timesteps per wave -> halves B-fragment traffic.
__global__ __launch_bounds__(256) void gemm_l1(
  const h8* __restrict__ Af,
  const h8* __restrict__ WpF, const h8* __restrict__ WpB,
  const float* __restrict__ bihF, const float* __restrict__ bhhF,
  const float* __restrict__ bihB, const float* __restrict__ bhhB,
  _Float16* __restrict__ GpF, _Float16* __restrict__ GpB)
{
  const int wv = threadIdx.x >> 6;
  const int l  = threadIdx.x & 63;
  const int mg = blockIdx.x % 72;
  const int tg = blockIdx.x / 72;        // 0..99
  const int mt0 = mg*4 + wv;             // 0..287
  const int mt1 = mt0 + 288;             // 288..575
  const int dir = tg / 50;
  const int Tb  = (tg % 50) * 4;
  const h8* Wp = dir ? WpB : WpF;
  const float* bih = dir ? bihB : bihF;
  const float* bhh = dir ? bhhB : bhhF;
  _Float16* Gp = dir ? GpB : GpF;

  const h8* a0 = Af + (size_t)mt0*3200 + l;
  const h8* a1 = Af + (size_t)mt1*3200 + l;
  f4 acc0[4], acc1[4];
  #pragma unroll
  for(int j=0;j<4;++j){
    acc0[j][0]=0.f; acc0[j][1]=0.f; acc0[j][2]=0.f; acc0[j][3]=0.f;
    acc1[j][0]=0.f; acc1[j][1]=0.f; acc1[j][2]=0.f; acc1[j][3]=0.f;
  }
  for(int q=0;q<KQ_L1;++q){
    h8 av0 = a0[q*64];
    h8 av1 = a1[q*64];
    #pragma unroll
    for(int j=0;j<4;++j){
      h8 bv = Wp[((size_t)(Tb+j)*KQ_L1 + q)*64 + l];
      acc0[j] = __builtin_amdgcn_mfma_f32_16x16x32_f16(av0, bv, acc0[j], 0, 0, 0);
      acc1[j] = __builtin_amdgcn_mfma_f32_16x16x32_f16(av1, bv, acc1[j], 0, 0, 0);
    }
  }
  const int c = l & 15;
  #pragma unroll
  for(int j=0;j<4;++j){
    int T = Tb + j;
    int n = (c&3)*800 + T*4 + (c>>2);
    float bias = bih[n] + bhh[n];
    h4 o0, o1;
    o0[0]=(_Float16)(acc0[j][0]+bias); o0[1]=(_Float16)(acc0[j][1]+bias);
    o0[2]=(_Float16)(acc0[j][2]+bias); o0[3]=(_Float16)(acc0[j][3]+bias);
    o1[0]=(_Float16)(acc1[j][0]+bias); o1[1]=(_Float16)(acc1[j][1]+bias);
    o1[2]=(_Float16)(acc1[j][2]+bias); o1[3]=(_Float16)(acc1[j][3]+bias);
    *(h4*)(Gp + (((size_t)mt0*NT + T)*64 + l)*4) = o0;
    *(h4*)(Gp + (((size_t)mt1*NT + T)*64 + l)*4) = o1;
  }
}

// ---------------- persistent LSTM layer (wave-autonomous LLC sync) -----------
// 100 blocks x 256 threads: 400 waves, one gate tile each. Blocks 0..49 fwd,
// 50..99 bwd. No LDS, no __syncthreads. Per-WAVE monotone flags (200/dir).
// Producer h-stores: sc1 (write-through to LLC), ordered before flag (vmcnt).
// Consumer staging: PLAIN cached loads, direct to registers (fragment layout
// makes lane l <-> unit q*64+l). Safe because h addresses are write-once per
// dispatch and kernel start invalidates L2s: a line can only enter an XCD L2
// after some wave on it observed the flag, hence after LLC has the data.
__global__ __launch_bounds__(256,1) void lstm_kernel(
  const h8* __restrict__ WpF, const h8* __restrict__ WpB,
  const _Float16* __restrict__ GpF, const _Float16* __restrict__ GpB,
  h8* __restrict__ hfrag, int* __restrict__ flags)
{
  const int tid = threadIdx.x;
  const int wv  = tid >> 6;
  const int l   = tid & 63;
  const bool bwd = blockIdx.x >= 50;
  const int T = ((bwd ? (int)blockIdx.x - 50 : (int)blockIdx.x) << 2) + wv;  // 0..199
  const h8* Wp = bwd ? WpB : WpF;
  const _Float16* Gp = bwd ? GpB : GpF;
  const int dirOff = bwd ? 1600 : 0;
  int* flg = flags + (bwd ? 256 : 0);

  h8 Bf[KQ_HH];
  #pragma unroll
  for(int q=0;q<KQ_HH;++q) Bf[q] = Wp[(T*KQ_HH + q)*64 + l];

  float cs[4] = {0.f,0.f,0.f,0.f};
  const int lb = l & ~3;
  const int qT = T>>3, subT = (T&7)>>1, halfT = T&1;
  // poll address: lane b<50 watches flag words 4b..4b+3 (covers 200 waves)
  const unsigned long long fa = (unsigned long long)(flg + (l < 50 ? l*4 : 0));

  for(int s=0; s<L_SEQ; ++s){
    const int t = bwd ? (L_SEQ-1-s) : s;

    // prefetch Gp[t] (plain cached; lands during the poll)
    h4 gp4 = *(const h4*)(Gp + (((size_t)t*NT + T)*64 + l)*4);

    h8 a[KQ_HH];
    if(s > 0){
      // wave-parallel poll of all 200 per-wave monotone counters
      v4i fv;
      for(;;){
        asm volatile("global_load_dwordx4 %0, %1, off sc1\n\ts_waitcnt vmcnt(0)"
                     : "=v"(fv) : "v"(fa) : "memory");
        bool ok = (l >= 50) || (fv[0] >= s && fv[1] >= s && fv[2] >= s && fv[3] >= s);
        if(__all(ok)) break;
        __builtin_amdgcn_s_sleep(1);
      }
      // stage h[t_prev]: 25 plain cached loads straight into registers
      const h8* src = hfrag + (size_t)(bwd ? t+1 : t-1)*3200 + dirOff + l;
      #pragma unroll
      for(int q=0;q<KQ_HH;++q) a[q] = src[q*64];
    }

    // gates = Gp[t] + h_prev @ W_hh^T
    f4 acc[4];
    acc[0][0]=(float)gp4[0]; acc[0][1]=(float)gp4[1]; acc[0][2]=(float)gp4[2]; acc[0][3]=(float)gp4[3];
    #pragma unroll
    for(int j=1;j<4;++j){ acc[j][0]=0.f; acc[j][1]=0.f; acc[j][2]=0.f; acc[j][3]=0.f; }
    if(s > 0){
      #pragma unroll
      for(int q=0;q<KQ_HH;++q)
        acc[q&3] = __builtin_amdgcn_mfma_f32_16x16x32_f16(a[q], Bf[q], acc[q&3], 0,0,0);
    }
    f4 g = (acc[0]+acc[1]) + (acc[2]+acc[3]);

    float hv[4];
    #pragma unroll
    for(int r=0;r<4;++r){
      float iv = __shfl(g[r], lb+0, 64);
      float fv_ = __shfl(g[r], lb+1, 64);
      float gv = __shfl(g[r], lb+2, 64);
      float ov = __shfl(g[r], lb+3, 64);
      float cn = sigmoidf_(fv_)*cs[r] + sigmoidf_(iv)*tanhf_(gv);
      cs[r] = cn;
      hv[r] = sigmoidf_(ov)*tanhf_(cn);
    }

    // store h[t] in fragment layout via sc1 (write-through to LLC):
    // wave writes 16 x 8B inside its 256B window
    h8* hb = hfrag + (size_t)t*3200 + dirOff + qT*64 + subT*16;
    #pragma unroll
    for(int r=0;r<4;++r){
      const int srcl = (l&3) << 4;
      float v0 = __shfl(hv[r], srcl+0, 64);
      float v1 = __shfl(hv[r], srcl+4, 64);
      float v2 = __shfl(hv[r], srcl+8, 64);
      float v3 = __shfl(hv[r], srcl+12, 64);
      if((l >> 2) == r){
        h4 o; o[0]=(_Float16)v0; o[1]=(_Float16)v1; o[2]=(_Float16)v2; o[3]=(_Float16)v3;
        int mrow = (l&3)*4 + r;
        unsigned long long ad = (unsigned long long)((char*)(hb + mrow) + halfT*8);
        v2i ov = __builtin_bit_cast(v2i, o);
        asm volatile("global_store_dwordx2 %0, %1, off sc1" : : "v"(ad), "v"(ov) : "memory");
      }
    }
    asm volatile("s_waitcnt vmcnt(0)" : : : "memory");   // h committed to LLC
    if(l == 0 && s != L_SEQ-1){
      int val = s + 1;
      unsigned long long fa2 = (unsigned long long)(flg + T);
      asm volatile("global_store_dword %0, %1, off sc1" : : "v"(fa2), "v"(val) : "memory");
    }
  }
}

// ---------------- head: fc -> softmax-free atan2 -> SRF ---------------------
__global__ void head_kernel(const h8* __restrict__ h1f,
                            const float* __restrict__ fcw, const float* __restrict__ fcb,
                            const float* __restrict__ alphabet,
                            const float* __restrict__ bl, const float* __restrict__ ba,
                            float* __restrict__ srf)
{
  __shared__ h8 sh8[16*201];   // stride 201 units (3216B = 804 words, %32=4)
  __shared__ float slog[960];
  __shared__ float smax[16];
  __shared__ float sphi[48];
  const int t = blockIdx.x, tid = threadIdx.x;
  const h8* src = h1f + (size_t)t*3200;
  for(int u=tid; u<3200; u+=256){
    int q2 = u >> 6, r = u & 63, sub = r >> 4, m = r & 15;
    sh8[m*201 + (q2<<2) + sub] = src[u];
  }
  __syncthreads();
  for(int it=tid; it<960; it+=256){
    int j = it >> 4, b = it & 15;
    float acc = fcb[j];
    const float4* wr = (const float4*)(fcw + (size_t)j*1600);
    const h8* hr = sh8 + b*201;
    for(int k=0;k<200;++k){
      h8 hv = hr[k];
      float4 w0 = wr[2*k], w1 = wr[2*k+1];
      acc += w0.x*(float)hv[0] + w0.y*(float)hv[1] + w0.z*(float)hv[2] + w0.w*(float)hv[3]
           + w1.x*(float)hv[4] + w1.y*(float)hv[5] + w1.z*(float)hv[6] + w1.w*(float)hv[7];
    }
    slog[b*60 + j] = acc;
  }
  __syncthreads();
  if(tid < 16){
    float mx = -1e30f;
    for(int j=0;j<60;++j) mx = fmaxf(mx, slog[tid*60+j]);
    smax[tid] = mx;
  }
  __syncthreads();
  if(tid < 48){
    int b = tid/3, ax = tid%3;
    float s=0.f, c=0.f, mx = smax[b];
    for(int j=0;j<60;++j){
      float e = __expf(slog[b*60+j] - mx);
      float al = alphabet[j*3 + ax];
      s += e*__sinf(al); c += e*__cosf(al);
    }
    sphi[b*3+ax] = atan2f(s, c);   // softmax denominator cancels in atan2
  }
  __syncthreads();
  if(tid < 144){
    int jj = tid/48; int r_ = tid%48; int b = r_/3, ax = r_%3;
    float rr = bl[jj], th = ba[jj], ph = sphi[b*3+jj];
    float v = (ax==0) ? rr*__cosf(th)
            : (ax==1) ? rr*__cosf(ph)*__sinf(th)
                      : rr*__sinf(ph)*__sinf(th);
    srf[(((size_t)(3*t+jj))*16 + b)*3 + ax] = v;
  }
}

// ---------------- pNeRF: 384 chain scans + 23 fragment stitches -------------
__device__ __forceinline__ void frame_cols(
  float ax,float ay,float az, float bx,float by,float bz, float cx,float cy,float cz,
  float* R)
{
  float ux=cx-bx, uy=cy-by, uz=cz-bz;
  float ir = rsqrtf(ux*ux+uy*uy+uz*uz);
  float bcx=ux*ir, bcy=uy*ir, bcz=uz*ir;
  float px=bx-ax, py=by-ay, pz=bz-az;
  float nx=py*bcz-pz*bcy, ny=pz*bcx-px*bcz, nz=px*bcy-py*bcx;
  float in_ = rsqrtf(nx*nx+ny*ny+nz*nz);
  nx*=in_; ny*=in_; nz*=in_;
  float mx=ny*bcz-nz*bcy, my=nz*bcx-nx*bcz, mz=nx*bcy-ny*bcx;
  R[0]=bcx;R[1]=bcy;R[2]=bcz; R[3]=mx;R[4]=my;R[5]=mz; R[6]=nx;R[7]=ny;R[8]=nz;
}

__global__ void pnerf_kernel(const float* __restrict__ srf,
                             float* __restrict__ frag, float* __restrict__ out)
{
  __shared__ float tail[3][16][3];
  __shared__ float sR[16][9];
  __shared__ float sorg[16][3];
  const int tid = threadIdx.x;
  if(tid < 384){
    int k = tid >> 4, b = tid & 15;
    float ax=-0.70710678f, ay=1.22474487f, az=0.f;
    float bx=-1.41421356f, by=0.f, bz=0.f;
    float cx=0.f, cy=0.f, cz=0.f;
    for(int f=0; f<72; ++f){
      const float* ct = srf + (((size_t)(k*72+f))*16 + b)*3;
      float t0=ct[0], t1=ct[1], t2=ct[2];
      float R[9];
      frame_cols(ax,ay,az, bx,by,bz, cx,cy,cz, R);
      float dx = cx + R[0]*t0 + R[3]*t1 + R[6]*t2;
      float dy = cy + R[1]*t0 + R[4]*t1 + R[7]*t2;
      float dz = cz + R[2]*t0 + R[5]*t1 + R[8]*t2;
      float* fr = frag + (((size_t)(f*24+k))*16 + b)*3;
      fr[0]=dx; fr[1]=dy; fr[2]=dz;
      if(k == 0){
        float* o = out + ((size_t)(f*16)+b)*3;
        o[0]=dx; o[1]=dy; o[2]=dz;
        if(f >= 69){ tail[f-69][b][0]=dx; tail[f-69][b][1]=dy; tail[f-69][b][2]=dz; }
      }
      ax=bx; ay=by; az=bz;  bx=cx; by=cy; bz=cz;  cx=dx; cy=dy; cz=dz;
    }
  }
  __syncthreads();
  for(int kk=1; kk<24; ++kk){
    if(tid < 16){
      int b = tid;
      frame_cols(tail[0][b][0],tail[0][b][1],tail[0][b][2],
                 tail[1][b][0],tail[1][b][1],tail[1][b][2],
                 tail[2][b][0],tail[2][b][1],tail[2][b][2], &sR[b][0]);
      sorg[b][0]=tail[2][b][0]; sorg[b][1]=tail[2][b][1]; sorg[b][2]=tail[2][b][2];
    }
    __syncthreads();
    for(int idx=tid; idx<1152; idx+=blockDim.x){
      int f = idx >> 4, b = idx & 15;
      const float* v = frag + (((size_t)(f*24+kk))*16 + b)*3;
      float vx=v[0], vy=v[1], vz=v[2];
      float gx = sorg[b][0] + sR[b][0]*vx + sR[b][3]*vy + sR[b][6]*vz;
      float gy = sorg[b][1] + sR[b][1]*vx + sR[b][4]*vy + sR[b][7]*vz;
      float gz = sorg[b][2] + sR[b][2]*vx + sR[b][5]*vy + sR[b][8]*vz;
      float* o = out + (((size_t)(kk*72+f))*16 + b)*3;
      o[0]=gx; o[1]=gy; o[2]=gz;
      if(f >= 69){ tail[f-69][b][0]=gx; tail[f-69][b][1]=gy; tail[f-69][b][2]=gz; }
    }
    __syncthreads();
  }
}

// ---------------------------------------------------------------------------
extern "C" void kernel_launch(void* const* d_in, const int* in_sizes, int n_in,
                              void* d_out, int out_size, void* d_ws, size_t ws_size,
                              hipStream_t stream)
{
  (void)in_sizes; (void)n_in; (void)out_size; (void)ws_size;
  const int*   seq  = (const int*)d_in[0];
  const float* pssm = (const float*)d_in[1];
  const float* w_ih_l0f=(const float*)d_in[3];  const float* w_hh_l0f=(const float*)d_in[4];
  const float* b_ih_l0f=(const float*)d_in[5];  const float* b_hh_l0f=(const float*)d_in[6];
  const float* w_ih_l0b=(const float*)d_in[7];  const float* w_hh_l0b=(const float*)d_in[8];
  const float* b_ih_l0b=(const float*)d_in[9];  const float* b_hh_l0b=(const float*)d_in[10];
  const float* w_ih_l1f=(const float*)d_in[11]; const float* w_hh_l1f=(const float*)d_in[12];
  const float* b_ih_l1f=(const float*)d_in[13]; const float* b_hh_l1f=(const float*)d_in[14];
  const float* w_ih_l1b=(const float*)d_in[15]; const float* w_hh_l1b=(const float*)d_in[16];
  const float* b_ih_l1b=(const float*)d_in[17]; const float* b_hh_l1b=(const float*)d_in[18];
  const float* fc_w=(const float*)d_in[19];     const float* fc_b=(const float*)d_in[20];
  const float* alphabet=(const float*)d_in[21];
  const float* bl=(const float*)d_in[22];       const float* ba=(const float*)d_in[23];
  float* out = (float*)d_out;

  char* ws = (char*)d_ws;
  size_t o = 0;
  auto alloc = [&](size_t bytes){ size_t r = o; o = (o + bytes + 255) & ~(size_t)255; return r; };
  size_t o_wphh = alloc(4ull*320000*16);   // 20.48 MB  W_hh frags (4 dirs)
  size_t o_wp1  = alloc(2ull*640000*16);   // 20.48 MB  W_ih_l1 frags
  size_t o_wp0  = alloc(2ull*25600*16);    //  0.82 MB  W_ih_l0 frags (padded K=64)
  size_t o_gpf  = alloc(2ull*29491200);    // 58.98 MB  Gp fwd
  size_t o_gpb  = alloc(2ull*29491200);    // 58.98 MB  Gp bwd
  size_t o_h0   = alloc(16ull*576*3200);   // 29.49 MB  h0 frag layout (h8 units)
  size_t o_h1   = alloc(16ull*576*3200);   // 29.49 MB  h1 frag layout
  size_t o_x    = alloc(2ull*589824);      //  1.18 MB  x f16 (9216,64)
  size_t o_srf  = alloc(4ull*82944);       //  SRF
  size_t o_frag = alloc(4ull*82944);       //  pnerf fragments
  size_t o_flag = alloc(4ull*1024);        //  per-wave flags, 4 regions x 256

  h8* wp_hh = (h8*)(ws + o_wphh);
  h8* wp1   = (h8*)(ws + o_wp1);
  h8* wp0   = (h8*)(ws + o_wp0);
  _Float16* gpf = (_Float16*)(ws + o_gpf);
  _Float16* gpb = (_Float16*)(ws + o_gpb);
  h8* h0    = (h8*)(ws + o_h0);
  h8* h1    = (h8*)(ws + o_h1);
  _Float16* x = (_Float16*)(ws + o_x);
  float* srf    = (float*)(ws + o_srf);
  float* frag   = (float*)(ws + o_frag);
  int* flags    = (int*)(ws + o_flag);

  init_kernel<<<4, 256, 0, stream>>>(flags);
  build_x<<<2304, 256, 0, stream>>>(seq, pssm, x);
  prep_w<<<10200, 256, 0, stream>>>(w_hh_l0f, w_hh_l0b, w_hh_l1f, w_hh_l1b,
                                    w_ih_l1f, w_ih_l1b, w_ih_l0f, w_ih_l0b,
                                    wp_hh, wp1, wp0);
  // layer 0 input projection
  gemm_l0<<<14400, 256, 0, stream>>>(x, wp0, wp0 + 25600,
                                     b_ih_l0f, b_hh_l0f, b_ih_l0b, b_hh_l0b, gpf, gpb);
  // layer 0 recurrence (flag region 0)
  lstm_kernel<<<100, 256, 0, stream>>>(wp_hh, wp_hh + 320000, gpf, gpb, h0, flags);
  // layer 1 input projection (h0 fragment layout, 2 timesteps/wave)
  gemm_l1<<<7200, 256, 0, stream>>>(h0, wp1, wp1 + 640000,
                                    b_ih_l1f, b_hh_l1f, b_ih_l1b, b_hh_l1b, gpf, gpb);
  // layer 1 recurrence (flag region 2)
  lstm_kernel<<<100, 256, 0, stream>>>(wp_hh + 640000, wp_hh + 960000, gpf, gpb, h1,
                                       flags + 512);
  // fc head -> torsions -> SRF
  head_kernel<<<576, 256, 0, stream>>>(h1, fc_w, fc_b, alphabet, bl, ba, srf);
  // geometric chain
  pnerf_kernel<<<1, 512, 0, stream>>>(srf, frag, out);
}

// Round 7
// 5866.698 us; speedup vs baseline: 1.3844x; 1.3844x over previous
//
#include <hip/hip_runtime.h>
#include <hip/hip_fp16.h>

// Problem constants
#define L_SEQ 576
#define BATCH 16
#define HIDDEN 800
#define NT 200      // N tiles per direction (3200/16)
#define KQ_HH 25    // K chunks for W_hh (800/32)
#define KQ_L1 50    // 1600/32
#define KQ_L0 2     // padded 64/32

typedef _Float16 h8 __attribute__((ext_vector_type(8)));
typedef _Float16 h4 __attribute__((ext_vector_type(4)));
typedef float f4 __attribute__((ext_vector_type(4)));
typedef int v4i __attribute__((ext_vector_type(4)));
typedef int v2i __attribute__((ext_vector_type(2)));

__device__ __forceinline__ float sigmoidf_(float x){
  x = fminf(30.f, fmaxf(-30.f, x));
  return 1.f/(1.f+__expf(-x));
}
__device__ __forceinline__ float tanhf_(float x){
  x = fminf(15.f, fmaxf(-15.f, x));
  float e = __expf(2.f*x);
  return (e-1.f)/(e+1.f);
}

// ---------------- init: fill h0+h1 with f16 sentinel (bit14 set) ------------
// Real h outputs satisfy |h|<1 -> f16 bit14 == 0. Sentinel 0x7C00 has bit14=1.
__global__ void init_h(v4i* __restrict__ h){
  size_t i = (size_t)blockIdx.x*256 + threadIdx.x;
  v4i s = {0x7C007C00, 0x7C007C00, 0x7C007C00, 0x7C007C00};
  h[i] = s;
}

// ---------------- build x (L*B, 64) f16: [onehot(20) | pssm(21) | pad0] -----
__global__ void build_x(const int* __restrict__ seq, const float* __restrict__ pssm,
                        _Float16* __restrict__ x){
  int i = blockIdx.x*256 + threadIdx.x;
  if(i >= L_SEQ*BATCH*64) return;
  int m = i >> 6, k = i & 63;
  float v = 0.f;
  if(k < 20)      v = (seq[m]==k) ? 1.f : 0.f;
  else if(k < 41) v = pssm[m*21 + (k-20)];
  x[i] = (_Float16)v;
}

// ---------------- weight prep: fp32 -> f16 MFMA B-fragment layout ------------
// B-frag: lane l holds B[k=q*32+(l>>4)*8+j][n = tile*16 + (l&15)], j=0..7
// n-permutation: col c=l&15 -> unit u = T*4 + (c>>2), gate g = c&3, W row = g*800+u
__global__ void prep_w(
  const float* __restrict__ whh0f, const float* __restrict__ whh0b,
  const float* __restrict__ whh1f, const float* __restrict__ whh1b,
  const float* __restrict__ wih1f, const float* __restrict__ wih1b,
  const float* __restrict__ wih0f, const float* __restrict__ wih0b,
  h8* __restrict__ wp_hh, h8* __restrict__ wp1, h8* __restrict__ wp0)
{
  long idx = (long)blockIdx.x*256 + threadIdx.x;
  const long J1 = 4L*320000, J2 = 2L*640000, J3 = 2L*25600;
  if(idx < J1){
    int d = (int)(idx/320000); int r = (int)(idx%320000);
    int T = r/1600, q = (r%1600)/64, l = r&63;
    const float* W = (d==0)?whh0f:(d==1)?whh0b:(d==2)?whh1f:whh1b;
    int c = l&15; int n = (c&3)*800 + T*4 + (c>>2);
    const float* src = W + (size_t)n*800 + q*32 + ((l>>4)<<3);
    h8 v;
    #pragma unroll
    for(int j=0;j<8;++j) v[j] = (_Float16)src[j];
    wp_hh[idx] = v;
  } else if(idx < J1+J2){
    long i2 = idx - J1;
    int d = (int)(i2/640000); int r = (int)(i2%640000);
    int T = r/3200, q = (r%3200)/64, l = r&63;
    const float* W = d ? wih1b : wih1f;
    int c = l&15; int n = (c&3)*800 + T*4 + (c>>2);
    const float* src = W + (size_t)n*1600 + q*32 + ((l>>4)<<3);
    h8 v;
    #pragma unroll
    for(int j=0;j<8;++j) v[j] = (_Float16)src[j];
    wp1[i2] = v;
  } else if(idx < J1+J2+J3){
    long i3 = idx - J1 - J2;
    int d = (int)(i3/25600); int r = (int)(i3%25600);
    int T = r/128, q = (r%128)/64, l = r&63;
    const float* W = d ? wih0b : wih0f;
    int c = l&15; int n = (c&3)*800 + T*4 + (c>>2);
    int k0 = q*32 + ((l>>4)<<3);
    h8 v;
    #pragma unroll
    for(int j=0;j<8;++j){ int k = k0+j; v[j] = (_Float16)((k<41)? W[(size_t)n*41+k] : 0.f); }
    wp0[i3] = v;
  }
}

// ------------- layer-0 input projection (x row-major, lda=64) ---------------
__global__ __launch_bounds__(256) void gemm_l0(
  const _Float16* __restrict__ A,
  const h8* __restrict__ WpF, const h8* __restrict__ WpB,
  const float* __restrict__ bihF, const float* __restrict__ bhhF,
  const float* __restrict__ bihB, const float* __restrict__ bhhB,
  _Float16* __restrict__ GpF, _Float16* __restrict__ GpB)
{
  const int wv = threadIdx.x >> 6;
  const int l  = threadIdx.x & 63;
  const int mg = blockIdx.x % 144;
  const int tg = blockIdx.x / 144;       // 0..99
  const int mt = mg*4 + wv;              // 0..575
  const int dir = tg / 50;
  const int Tb  = (tg % 50) * 4;
  const h8* Wp = dir ? WpB : WpF;
  const float* bih = dir ? bihB : bihF;
  const float* bhh = dir ? bhhB : bhhF;
  _Float16* Gp = dir ? GpB : GpF;

  const _Float16* ab = A + (size_t)(mt*16 + (l&15))*64 + ((l>>4)<<3);
  f4 acc[4] = {{0.f,0.f,0.f,0.f},{0.f,0.f,0.f,0.f},{0.f,0.f,0.f,0.f},{0.f,0.f,0.f,0.f}};
  for(int q=0;q<KQ_L0;++q){
    h8 av = *(const h8*)(ab + q*32);
    #pragma unroll
    for(int j=0;j<4;++j){
      h8 bv = Wp[((size_t)(Tb+j)*KQ_L0 + q)*64 + l];
      acc[j] = __builtin_amdgcn_mfma_f32_16x16x32_f16(av, bv, acc[j], 0, 0, 0);
    }
  }
  const int c = l & 15;
  #pragma unroll
  for(int j=0;j<4;++j){
    int T = Tb + j;
    int n = (c&3)*800 + T*4 + (c>>2);
    float bias = bih[n] + bhh[n];
    h4 o;
    o[0]=(_Float16)(acc[j][0]+bias); o[1]=(_Float16)(acc[j][1]+bias);
    o[2]=(_Float16)(acc[j][2]+bias); o[3]=(_Float16)(acc[j][3]+bias);
    *(h4*)(Gp + (((size_t)mt*NT + T)*64 + l)*4) = o;
  }
}

// ------------- layer-1 input projection (h0 in fragment layout) --------------
// 2 timesteps per wave -> halves B-fragment traffic.
__global__ __launch_bounds__(256) void gemm_l1(
  const h8* __restrict__ Af,
  const h8* __restrict__ WpF, const h8* __restrict__ WpB,
  const float* __restrict__ bihF, const float* __restrict__ bhhF,
  const float* __restrict__ bihB, const float* __restrict__ bhhB,
  _Float16* __restrict__ GpF, _Float16* __restrict__ GpB)
{
  const int wv = threadIdx.x >> 6;
  const int l  = threadIdx.x & 63;
  const int mg = blockIdx.x % 72;
  const int tg = blockIdx.x / 72;        // 0..99
  const int mt0 = mg*4 + wv;             // 0..287
  const int mt1 = mt0 + 288;             // 288..575
  const int dir = tg / 50;
  const int Tb  = (tg % 50) * 4;
  const h8* Wp = dir ? WpB : WpF;
  const float* bih = dir ? bihB : bihF;
  const float* bhh = dir ? bhhB : bhhF;
  _Float16* Gp = dir ? GpB : GpF;

  const h8* a0 = Af + (size_t)mt0*3200 + l;
  const h8* a1 = Af + (size_t)mt1*3200 + l;
  f4 acc0[4], acc1[4];
  #pragma unroll
  for(int j=0;j<4;++j){
    acc0[j][0]=0.f; acc0[j][1]=0.f; acc0[j][2]=0.f; acc0[j][3]=0.f;
    acc1[j][0]=0.f; acc1[j][1]=0.f; acc1[j][2]=0.f; acc1[j][3]=0.f;
  }
  for(int q=0;q<KQ_L1;++q){
    h8 av0 = a0[q*64];
    h8 av1 = a1[q*64];
    #pragma unroll
    for(int j=0;j<4;++j){
      h8 bv = Wp[((size_t)(Tb+j)*KQ_L1 + q)*64 + l];
      acc0[j] = __builtin_amdgcn_mfma_f32_16x16x32_f16(av0, bv, acc0[j], 0, 0, 0);
      acc1[j] = __builtin_amdgcn_mfma_f32_16x16x32_f16(av1, bv, acc1[j], 0, 0, 0);
    }
  }
  const int c = l & 15;
  #pragma unroll
  for(int j=0;j<4;++j){
    int T = Tb + j;
    int n = (c&3)*800 + T*4 + (c>>2);
    float bias = bih[n] + bhh[n];
    h4 o0, o1;
    o0[0]=(_Float16)(acc0[j][0]+bias); o0[1]=(_Float16)(acc0[j][1]+bias);
    o0[2]=(_Float16)(acc0[j][2]+bias); o0[3]=(_Float16)(acc0[j][3]+bias);
    o1[0]=(_Float16)(acc1[j][0]+bias); o1[1]=(_Float16)(acc1[j][1]+bias);
    o1[2]=(_Float16)(acc1[j][2]+bias); o1[3]=(_Float16)(acc1[j][3]+bias);
    *(h4*)(Gp + (((size_t)mt0*NT + T)*64 + l)*4) = o0;
    *(h4*)(Gp + (((size_t)mt1*NT + T)*64 + l)*4) = o1;
  }
}

// ---------------- persistent LSTM layer (sentinel-sync, flag-free) -----------
// 100 blocks x 256 threads: 400 waves, one gate tile each. Blocks 0..49 fwd,
// 50..99 bwd. No LDS, no flags, no barriers.
// Producers: 16 x 8B sc1 stores (write-through to LLC), then move on.
// Consumers: poll-load the 25 fragment chunks with sc1; ready when no f16 has
// bit14 set (real |h|<1 -> bit14==0; sentinel 0x7C00 -> bit14==1).
// CRITICAL: the s_waitcnt asm takes all 25 w[] as "+v" operands so every read
// of w[] is data-dependent on it -- without this the compiler schedules the
// sentinel check before the waitcnt and reads stale registers (round-6 bug).
__global__ __launch_bounds__(256,1) void lstm_kernel(
  const h8* __restrict__ WpF, const h8* __restrict__ WpB,
  const _Float16* __restrict__ GpF, const _Float16* __restrict__ GpB,
  h8* __restrict__ hfrag)
{
  const int tid = threadIdx.x;
  const int wv  = tid >> 6;
  const int l   = tid & 63;
  const bool bwd = blockIdx.x >= 50;
  const int T = ((bwd ? (int)blockIdx.x - 50 : (int)blockIdx.x) << 2) + wv;  // 0..199
  const h8* Wp = bwd ? WpB : WpF;
  const _Float16* Gp = bwd ? GpB : GpF;
  const int dirOff = bwd ? 1600 : 0;

  h8 Bf[KQ_HH];
  #pragma unroll
  for(int q=0;q<KQ_HH;++q) Bf[q] = Wp[(T*KQ_HH + q)*64 + l];

  float cs[4] = {0.f,0.f,0.f,0.f};
  const int lb = l & ~3;
  const int qT = T>>3, subT = (T&7)>>1, halfT = T&1;

  for(int s=0; s<L_SEQ; ++s){
    const int t = bwd ? (L_SEQ-1-s) : s;

    // prefetch Gp[t] (plain cached)
    h4 gp4 = *(const h4*)(Gp + (((size_t)t*NT + T)*64 + l)*4);

    #pragma unroll
    for(int q=0;q<KQ_HH;++q) asm volatile("" : "+v"(Bf[q]));   // keep resident

    v4i w[KQ_HH];
    if(s > 0){
      const h8* src = hfrag + (size_t)(bwd ? t+1 : t-1)*3200 + dirOff + l;
      for(;;){
        #pragma unroll
        for(int q=0;q<KQ_HH;++q){
          unsigned long long ad = (unsigned long long)(src + q*64);
          asm volatile("global_load_dwordx4 %0, %1, off sc1"
                       : "=v"(w[q]) : "v"(ad) : "memory");
        }
        // waitcnt with all 25 results tied: orders every subsequent read
        asm volatile("s_waitcnt vmcnt(0)"
          : "+v"(w[0]),"+v"(w[1]),"+v"(w[2]),"+v"(w[3]),"+v"(w[4]),
            "+v"(w[5]),"+v"(w[6]),"+v"(w[7]),"+v"(w[8]),"+v"(w[9]),
            "+v"(w[10]),"+v"(w[11]),"+v"(w[12]),"+v"(w[13]),"+v"(w[14]),
            "+v"(w[15]),"+v"(w[16]),"+v"(w[17]),"+v"(w[18]),"+v"(w[19]),
            "+v"(w[20]),"+v"(w[21]),"+v"(w[22]),"+v"(w[23]),"+v"(w[24])
          :
          : "memory");
        int orac = 0;
        #pragma unroll
        for(int q=0;q<KQ_HH;++q) orac |= (w[q][0]|w[q][1]) | (w[q][2]|w[q][3]);
        if(__all((orac & 0x40004000) == 0)) break;
        __builtin_amdgcn_s_sleep(1);
      }
    }

    // gates = Gp[t] + h_prev @ W_hh^T
    f4 acc[4];
    acc[0][0]=(float)gp4[0]; acc[0][1]=(float)gp4[1]; acc[0][2]=(float)gp4[2]; acc[0][3]=(float)gp4[3];
    #pragma unroll
    for(int j=1;j<4;++j){ acc[j][0]=0.f; acc[j][1]=0.f; acc[j][2]=0.f; acc[j][3]=0.f; }
    if(s > 0){
      #pragma unroll
      for(int q=0;q<KQ_HH;++q)
        acc[q&3] = __builtin_amdgcn_mfma_f32_16x16x32_f16(
                     __builtin_bit_cast(h8, w[q]), Bf[q], acc[q&3], 0,0,0);
    }
    f4 g = (acc[0]+acc[1]) + (acc[2]+acc[3]);

    float hv[4];
    #pragma unroll
    for(int r=0;r<4;++r){
      float iv = __shfl(g[r], lb+0, 64);
      float fv_ = __shfl(g[r], lb+1, 64);
      float gv = __shfl(g[r], lb+2, 64);
      float ov = __shfl(g[r], lb+3, 64);
      float cn = sigmoidf_(fv_)*cs[r] + sigmoidf_(iv)*tanhf_(gv);
      cs[r] = cn;
      hv[r] = sigmoidf_(ov)*tanhf_(cn);
    }

    // store h[t] in fragment layout via sc1: wave writes 16 x 8B inside its
    // 256B window. No ack, no flag -- the data IS the signal.
    h8* hb = hfrag + (size_t)t*3200 + dirOff + qT*64 + subT*16;
    #pragma unroll
    for(int r=0;r<4;++r){
      const int srcl = (l&3) << 4;
      float v0 = __shfl(hv[r], srcl+0, 64);
      float v1 = __shfl(hv[r], srcl+4, 64);
      float v2 = __shfl(hv[r], srcl+8, 64);
      float v3 = __shfl(hv[r], srcl+12, 64);
      if((l >> 2) == r){
        h4 o; o[0]=(_Float16)v0; o[1]=(_Float16)v1; o[2]=(_Float16)v2; o[3]=(_Float16)v3;
        int mrow = (l&3)*4 + r;
        unsigned long long ad = (unsigned long long)((char*)(hb + mrow) + halfT*8);
        v2i ov = __builtin_bit_cast(v2i, o);
        asm volatile("global_store_dwordx2 %0, %1, off sc1" : : "v"(ad), "v"(ov) : "memory");
      }
    }
    // no vmcnt wait: next step's poll (or kernel end) drains the queue
  }
}

// ---------------- head: fc -> softmax-free atan2 -> SRF ---------------------
__global__ void head_kernel(const h8* __restrict__ h1f,
                            const float* __restrict__ fcw, const float* __restrict__ fcb,
                            const float* __restrict__ alphabet,
                            const float* __restrict__ bl, const float* __restrict__ ba,
                            float* __restrict__ srf)
{
  __shared__ h8 sh8[16*201];   // stride 201 units (3216B = 804 words, %32=4)
  __shared__ float slog[960];
  __shared__ float smax[16];
  __shared__ float sphi[48];
  const int t = blockIdx.x, tid = threadIdx.x;
  const h8* src = h1f + (size_t)t*3200;
  for(int u=tid; u<3200; u+=256){
    int q2 = u >> 6, r = u & 63, sub = r >> 4, m = r & 15;
    sh8[m*201 + (q2<<2) + sub] = src[u];
  }
  __syncthreads();
  for(int it=tid; it<960; it+=256){
    int j = it >> 4, b = it & 15;
    float acc = fcb[j];
    const float4* wr = (const float4*)(fcw + (size_t)j*1600);
    const h8* hr = sh8 + b*201;
    for(int k=0;k<200;++k){
      h8 hv = hr[k];
      float4 w0 = wr[2*k], w1 = wr[2*k+1];
      acc += w0.x*(float)hv[0] + w0.y*(float)hv[1] + w0.z*(float)hv[2] + w0.w*(float)hv[3]
           + w1.x*(float)hv[4] + w1.y*(float)hv[5] + w1.z*(float)hv[6] + w1.w*(float)hv[7];
    }
    slog[b*60 + j] = acc;
  }
  __syncthreads();
  if(tid < 16){
    float mx = -1e30f;
    for(int j=0;j<60;++j) mx = fmaxf(mx, slog[tid*60+j]);
    smax[tid] = mx;
  }
  __syncthreads();
  if(tid < 48){
    int b = tid/3, ax = tid%3;
    float s=0.f, c=0.f, mx = smax[b];
    for(int j=0;j<60;++j){
      float e = __expf(slog[b*60+j] - mx);
      float al = alphabet[j*3 + ax];
      s += e*__sinf(al); c += e*__cosf(al);
    }
    sphi[b*3+ax] = atan2f(s, c);   // softmax denominator cancels in atan2
  }
  __syncthreads();
  if(tid < 144){
    int jj = tid/48; int r_ = tid%48; int b = r_/3, ax = r_%3;
    float rr = bl[jj], th = ba[jj], ph = sphi[b*3+jj];
    float v = (ax==0) ? rr*__cosf(th)
            : (ax==1) ? rr*__cosf(ph)*__sinf(th)
                      : rr*__sinf(ph)*__sinf(th);
    srf[(((size_t)(3*t+jj))*16 + b)*3 + ax] = v;
  }
}

// ---------------- pNeRF: 384 chain scans + 23 fragment stitches -------------
__device__ __forceinline__ void frame_cols(
  float ax,float ay,float az, float bx,float by,float bz, float cx,float cy,float cz,
  float* R)
{
  float ux=cx-bx, uy=cy-by, uz=cz-bz;
  float ir = rsqrtf(ux*ux+uy*uy+uz*uz);
  float bcx=ux*ir, bcy=uy*ir, bcz=uz*ir;
  float px=bx-ax, py=by-ay, pz=bz-az;
  float nx=py*bcz-pz*bcy, ny=pz*bcx-px*bcz, nz=px*bcy-py*bcx;
  float in_ = rsqrtf(nx*nx+ny*ny+nz*nz);
  nx*=in_; ny*=in_; nz*=in_;
  float mx=ny*bcz-nz*bcy, my=nz*bcx-nx*bcz, mz=nx*bcy-ny*bcx;
  R[0]=bcx;R[1]=bcy;R[2]=bcz; R[3]=mx;R[4]=my;R[5]=mz; R[6]=nx;R[7]=ny;R[8]=nz;
}

__global__ void pnerf_kernel(const float* __restrict__ srf,
                             float* __restrict__ frag, float* __restrict__ out)
{
  __shared__ float tail[3][16][3];
  __shared__ float sR[16][9];
  __shared__ float sorg[16][3];
  const int tid = threadIdx.x;
  if(tid < 384){
    int k = tid >> 4, b = tid & 15;
    float ax=-0.70710678f, ay=1.22474487f, az=0.f;
    float bx=-1.41421356f, by=0.f, bz=0.f;
    float cx=0.f, cy=0.f, cz=0.f;
    for(int f=0; f<72; ++f){
      const float* ct = srf + (((size_t)(k*72+f))*16 + b)*3;
      float t0=ct[0], t1=ct[1], t2=ct[2];
      float R[9];
      frame_cols(ax,ay,az, bx,by,bz, cx,cy,cz, R);
      float dx = cx + R[0]*t0 + R[3]*t1 + R[6]*t2;
      float dy = cy + R[1]*t0 + R[4]*t1 + R[7]*t2;
      float dz = cz + R[2]*t0 + R[5]*t1 + R[8]*t2;
      float* fr = frag + (((size_t)(f*24+k))*16 + b)*3;
      fr[0]=dx; fr[1]=dy; fr[2]=dz;
      if(k == 0){
        float* o = out + ((size_t)(f*16)+b)*3;
        o[0]=dx; o[1]=dy; o[2]=dz;
        if(f >= 69){ tail[f-69][b][0]=dx; tail[f-69][b][1]=dy; tail[f-69][b][2]=dz; }
      }
      ax=bx; ay=by; az=bz;  bx=cx; by=cy; bz=cz;  cx=dx; cy=dy; cz=dz;
    }
  }
  __syncthreads();
  for(int kk=1; kk<24; ++kk){
    if(tid < 16){
      int b = tid;
      frame_cols(tail[0][b][0],tail[0][b][1],tail[0][b][2],
                 tail[1][b][0],tail[1][b][1],tail[1][b][2],
                 tail[2][b][0],tail[2][b][1],tail[2][b][2], &sR[b][0]);
      sorg[b][0]=tail[2][b][0]; sorg[b][1]=tail[2][b][1]; sorg[b][2]=tail[2][b][2];
    }
    __syncthreads();
    for(int idx=tid; idx<1152; idx+=blockDim.x){
      int f = idx >> 4, b = idx & 15;
      const float* v = frag + (((size_t)(f*24+kk))*16 + b)*3;
      float vx=v[0], vy=v[1], vz=v[2];
      float gx = sorg[b][0] + sR[b][0]*vx + sR[b][3]*vy + sR[b][6]*vz;
      float gy = sorg[b][1] + sR[b][1]*vx + sR[b][4]*vy + sR[b][7]*vz;
      float gz = sorg[b][2] + sR[b][2]*vx + sR[b][5]*vy + sR[b][8]*vz;
      float* o = out + (((size_t)(kk*72+f))*16 + b)*3;
      o[0]=gx; o[1]=gy; o[2]=gz;
      if(f >= 69){ tail[f-69][b][0]=gx; tail[f-69][b][1]=gy; tail[f-69][b][2]=gz; }
    }
    __syncthreads();
  }
}

// ---------------------------------------------------------------------------
extern "C" void kernel_launch(void* const* d_in, const int* in_sizes, int n_in,
                              void* d_out, int out_size, void* d_ws, size_t ws_size,
                              hipStream_t stream)
{
  (void)in_sizes; (void)n_in; (void)out_size; (void)ws_size;
  const int*   seq  = (const int*)d_in[0];
  const float* pssm = (const float*)d_in[1];
  const float* w_ih_l0f=(const float*)d_in[3];  const float* w_hh_l0f=(const float*)d_in[4];
  const float* b_ih_l0f=(const float*)d_in[5];  const float* b_hh_l0f=(const float*)d_in[6];
  const float* w_ih_l0b=(const float*)d_in[7];  const float* w_hh_l0b=(const float*)d_in[8];
  const float* b_ih_l0b=(const float*)d_in[9];  const float* b_hh_l0b=(const float*)d_in[10];
  const float* w_ih_l1f=(const float*)d_in[11]; const float* w_hh_l1f=(const float*)d_in[12];
  const float* b_ih_l1f=(const float*)d_in[13]; const float* b_hh_l1f=(const float*)d_in[14];
  const float* w_ih_l1b=(const float*)d_in[15]; const float* w_hh_l1b=(const float*)d_in[16];
  const float* b_ih_l1b=(const float*)d_in[17]; const float* b_hh_l1b=(const float*)d_in[18];
  const float* fc_w=(const float*)d_in[19];     const float* fc_b=(const float*)d_in[20];
  const float* alphabet=(const float*)d_in[21];
  const float* bl=(const float*)d_in[22];       const float* ba=(const float*)d_in[23];
  float* out = (float*)d_out;

  char* ws = (char*)d_ws;
  size_t o = 0;
  auto alloc = [&](size_t bytes){ size_t r = o; o = (o + bytes + 255) & ~(size_t)255; return r; };
  size_t o_wphh = alloc(4ull*320000*16);   // 20.48 MB  W_hh frags (4 dirs)
  size_t o_wp1  = alloc(2ull*640000*16);   // 20.48 MB  W_ih_l1 frags
  size_t o_wp0  = alloc(2ull*25600*16);    //  0.82 MB  W_ih_l0 frags (padded K=64)
  size_t o_gpf  = alloc(2ull*29491200);    // 58.98 MB  Gp fwd
  size_t o_gpb  = alloc(2ull*29491200);    // 58.98 MB  Gp bwd
  size_t o_h0   = alloc(16ull*576*3200);   // 29.49 MB  h0 frag layout (h8 units)
  size_t o_h1   = alloc(16ull*576*3200);   // 29.49 MB  h1 frag layout (contiguous after h0)
  size_t o_x    = alloc(2ull*589824);      //  1.18 MB  x f16 (9216,64)
  size_t o_srf  = alloc(4ull*82944);       //  SRF
  size_t o_frag = alloc(4ull*82944);       //  pnerf fragments

  h8* wp_hh = (h8*)(ws + o_wphh);
  h8* wp1   = (h8*)(ws + o_wp1);
  h8* wp0   = (h8*)(ws + o_wp0);
  _Float16* gpf = (_Float16*)(ws + o_gpf);
  _Float16* gpb = (_Float16*)(ws + o_gpb);
  h8* h0    = (h8*)(ws + o_h0);
  h8* h1    = (h8*)(ws + o_h1);
  _Float16* x = (_Float16*)(ws + o_x);
  float* srf    = (float*)(ws + o_srf);
  float* frag   = (float*)(ws + o_frag);

  // sentinel-init h0+h1 (contiguous: 2 x 576 x 3200 h8 = 3,686,400 v4i)
  init_h<<<14400, 256, 0, stream>>>((v4i*)(ws + o_h0));
  build_x<<<2304, 256, 0, stream>>>(seq, pssm, x);
  prep_w<<<10200, 256, 0, stream>>>(w_hh_l0f, w_hh_l0b, w_hh_l1f, w_hh_l1b,
                                    w_ih_l1f, w_ih_l1b, w_ih_l0f, w_ih_l0b,
                                    wp_hh, wp1, wp0);
  // layer 0 input projection
  gemm_l0<<<14400, 256, 0, stream>>>(x, wp0, wp0 + 25600,
                                     b_ih_l0f, b_hh_l0f, b_ih_l0b, b_hh_l0b, gpf, gpb);
  // layer 0 recurrence
  lstm_kernel<<<100, 256, 0, stream>>>(wp_hh, wp_hh + 320000, gpf, gpb, h0);
  // layer 1 input projection (h0 fragment layout, 2 timesteps/wave)
  gemm_l1<<<7200, 256, 0, stream>>>(h0, wp1, wp1 + 640000,
                                    b_ih_l1f, b_hh_l1f, b_ih_l1b, b_hh_l1b, gpf, gpb);
  // layer 1 recurrence
  lstm_kernel<<<100, 256, 0, stream>>>(wp_hh + 640000, wp_hh + 960000, gpf, gpb, h1);
  // fc head -> torsions -> SRF
  head_kernel<<<576, 256, 0, stream>>>(h1, fc_w, fc_b, alphabet, bl, ba, srf);
  // geometric chain
  pnerf_kernel<<<1, 512, 0, stream>>>(srf, frag, out);
}